// Round 13
// baseline (170.247 us; speedup 1.0000x reference)
//
#include <hip/hip_runtime.h>
#include <stdint.h>

typedef short short8 __attribute__((ext_vector_type(8)));
typedef float f32x4 __attribute__((ext_vector_type(4)));

#define KLAM 0.003f
// B=2, H=2048, L=4096, Lk=128, N = B*L = 8192, M2 = 2H = 4096

__device__ __forceinline__ uint16_t f2bf(float f) {
  union { float f; uint32_t u; } v; v.f = f;
  uint32_t r = v.u + 0x7fffu + ((v.u >> 16) & 1u);  // RNE
  return (uint16_t)(r >> 16);
}
__device__ __forceinline__ uint32_t pack_lo(uint32_t a, uint32_t b) { return (a & 0xffffu) | (b << 16); }
__device__ __forceinline__ uint32_t pack_hi(uint32_t a, uint32_t b) { return (a >> 16) | (b & 0xffff0000u); }
__device__ __forceinline__ int swzB(int n) { return ((n & 7) ^ ((n >> 3) & 7)); }

typedef __attribute__((address_space(3))) uint32_t* lds_u32p;
typedef const __attribute__((address_space(1))) uint32_t* gbl_u32p;
__device__ __forceinline__ void gload16(const void* g, void* l) {
  __builtin_amdgcn_global_load_lds((gbl_u32p)g, (lds_u32p)l, 16, 0, 0);
}

// ------- K2 (merged): blocks 0..4095 = depthwise FIR + u*D + GeLU; 4096..8191 = cast W -------
__global__ __launch_bounds__(256) void conv_cast_kernel(const float* __restrict__ u,
                                                        const float* __restrict__ kern,
                                                        const float* __restrict__ D,
                                                        uint16_t* __restrict__ X,
                                                        const float* __restrict__ W,
                                                        uint16_t* __restrict__ Wb) {
  int bid = blockIdx.x;
  if (bid >= 4096) {
    int i = ((bid - 4096) * 256 + threadIdx.x) * 8;
    float4 f0 = *(const float4*)(W + i);
    float4 f1 = *(const float4*)(W + i + 4);
    uint4 q;
    q.x = (uint32_t)f2bf(f0.x) | ((uint32_t)f2bf(f0.y) << 16);
    q.y = (uint32_t)f2bf(f0.z) | ((uint32_t)f2bf(f0.w) << 16);
    q.z = (uint32_t)f2bf(f1.x) | ((uint32_t)f2bf(f1.y) << 16);
    q.w = (uint32_t)f2bf(f1.z) | ((uint32_t)f2bf(f1.w) << 16);
    *(uint4*)(Wb + i) = q;
    return;
  }

  __shared__ __align__(16) float su[4096];
  __shared__ __align__(16) uint16_t ubf[4256];
  __shared__ __align__(16) uint16_t kR[176];
  __shared__ __align__(16) uint16_t stg[4][256];

  int tid = threadIdx.x;
  int bh = bid;
  int h = bh & 2047;
  int b = bh >> 11;
  int lane = tid & 63;
  int wv = tid >> 6;
  int ln15 = lane & 15;
  int g = lane >> 4;

  const float4* u4 = (const float4*)(u + (size_t)bh * 4096);
#pragma unroll
  for (int i = 0; i < 4; ++i) {
    float4 v = u4[i * 256 + tid];
    ((float4*)su)[i * 256 + tid] = v;
    uint2 p;
    p.x = (uint32_t)f2bf(v.x) | ((uint32_t)f2bf(v.y) << 16);
    p.y = (uint32_t)f2bf(v.z) | ((uint32_t)f2bf(v.w) << 16);
    *(uint2*)(ubf + 160 + (i * 256 + tid) * 4) = p;
  }
  if (tid < 40) { uint2 z; z.x = 0; z.y = 0; *(uint2*)(ubf + tid * 4) = z; }
  if (tid < 176) {
    int i = 159 - tid;
    uint16_t r = 0;
    if (i >= 0 && i < 128) {
      float kv = kern[h * 128 + i];
      float a = fabsf(kv) - KLAM;
      float s = (a > 0.f) ? (kv > 0.f ? a : -a) : 0.f;
      r = f2bf(s);
    }
    kR[tid] = r;
  }
  __syncthreads();

  float Dh = D[h];

  short8 bfr[5];
#pragma unroll
  for (int q = 0; q < 5; ++q) {
    int z0 = 143 - 32 * q - ln15 + 8 * g;
    union { short8 v; uint16_t s[8]; } t;
#pragma unroll
    for (int e = 0; e < 8; ++e) t.s[e] = kR[z0 + e];
    bfr[q] = t.v;
  }

#pragma unroll
  for (int it = 0; it < 4; ++it) {
    int T0 = (wv * 4 + it) * 256;
    f32x4 acc = {0.f, 0.f, 0.f, 0.f};
#pragma unroll
    for (int q = 0; q < 5; ++q) {
      const short8 a = *(const short8*)(ubf + 160 + T0 + 16 * ln15 - 16 - 32 * q + 8 * g);
      acc = __builtin_amdgcn_mfma_f32_16x16x32_bf16(a, bfr[q], acc, 0, 0, 0);
    }
#pragma unroll
    for (int r = 0; r < 4; ++r) {
      int m = 4 * g + r;
      int t = T0 + 16 * m + ln15;
      float y = acc[r] + Dh * su[t];
      float ge = 0.5f * y * (1.f + erff(y * 0.70710678118654752f));
      stg[wv][16 * m + ln15] = f2bf(ge);
    }
    uint2 v = *(uint2*)(&stg[wv][lane * 4]);
    *(uint2*)(X + (size_t)h * 8192 + (size_t)b * 4096 + T0 + lane * 4) = v;
  }
}

// ------- K2b: transpose X [2048][8192] -> XT [8192][2048] (bf16) -------
__global__ __launch_bounds__(256) void transpose_kernel(const uint16_t* __restrict__ X,
                                                        uint16_t* __restrict__ XT) {
  __shared__ uint16_t t[64][66];
  int tid = threadIdx.x;
  int bn = blockIdx.x & 127;   // n-tile
  int bk = blockIdx.x >> 7;    // k-tile
  int n0 = bn << 6, k0 = bk << 6;
  int cr = tid >> 3;           // 0..31
  int cc = (tid & 7) * 8;      // 0..56
#pragma unroll
  for (int p = 0; p < 2; ++p) {
    int kr = p * 32 + cr;
    uint4 v = *(const uint4*)(X + (size_t)(k0 + kr) * 8192 + n0 + cc);
    const uint16_t* s = (const uint16_t*)&v;
#pragma unroll
    for (int e = 0; e < 8; ++e) t[cc + e][kr] = s[e];
  }
  __syncthreads();
#pragma unroll
  for (int p = 0; p < 2; ++p) {
    int nl = p * 32 + cr;
    uint16_t d[8];
#pragma unroll
    for (int e = 0; e < 8; ++e) d[e] = t[nl][cc + e];
    *(uint4*)(XT + (size_t)(n0 + nl) * 2048 + k0 + cc) = *(uint4*)d;
  }
}

// ------- K3 v13: fully decoupled pipeline — every MFMA's operands read >=1 phase earlier -------
// P1: rd fbh(4);  stage BH(t+1); bar; MFMA a x nlo (fa_c, fbl_c from P4(t-1)); bar.
// P2: rd fgA(4);  stage AA(t+2); bar; MFMA a x nhi (fbh from P1); bar.
// P3: rd fgB(4);  stage BL(t+2); bar; MFMA g[mi0-1] x alln (fgA from P2); bar.
// P4: stage AG(t+2); vmcnt(6); bar; rd fa_n(8)+fbl_n(4); MFMA g[mi2-3] x alln (fgB from P3); bar.
// No manual lgkm. Register dbuf of fa/fbl via alternating arrays (x2-unrolled loop).
__global__ __launch_bounds__(512, 2) void gemm_glu_v13(const uint16_t* __restrict__ Wb,
                                                       const uint16_t* __restrict__ XT,
                                                       const float* __restrict__ bout,
                                                       float* __restrict__ out) {
  __shared__ __align__(16) char lds[131072];  // A[2][256][64]bf16 @0, B[2][256][64] @65536

  int tid = threadIdx.x;
  int lane = tid & 63;
  int wv = tid >> 6;          // 0..7
  int wr = wv >> 2;           // 0..1  (M half)
  int wc = wv & 3;            // 0..3  (N quarter)
  int ln15 = lane & 15;
  int g16 = lane >> 4;        // 0..3

  // XCD mapping: each XCD owns 4 bn-columns (XT slice 4MB ~ one L2), sweeps bm.
  int bid = blockIdx.x;
  int xcd = bid & 7, idx = bid >> 3;
  int bn = xcd * 4 + (idx & 3);
  int bm = idx >> 2;
  int mo0 = bm * 128, n0 = bn * 256;

  // ---- staging source pointers (pre-swizzled global, linear LDS dest) ----
  int lr8 = lane >> 3;
  int sb = (((lane & 7) ^ lr8) << 4);
  const char* pAA = (const char*)Wb + (size_t)(mo0 + wv * 16 + lr8) * 4096 + sb;
  const char* pAG = (const char*)Wb + (size_t)(2048 + mo0 + wv * 16 + lr8) * 4096 + sb;
  const char* pBL = (const char*)XT + (size_t)(n0 + wv * 16 + lr8) * 4096 + sb;
  const char* pBH = (const char*)XT + (size_t)(n0 + 128 + wv * 16 + lr8) * 4096 + sb;
  uint32_t ldW = wv * 2048;

  auto stAA = [&](int buf, const char* p) {
    char* d = lds + buf * 32768 + ldW;
    gload16(p, d); gload16(p + 32768, d + 1024);
  };
  auto stAG = [&](int buf, const char* p) {
    char* d = lds + buf * 32768 + 16384 + ldW;
    gload16(p, d); gload16(p + 32768, d + 1024);
  };
  auto stBL = [&](int buf, const char* p) {
    char* d = lds + 65536 + buf * 32768 + ldW;
    gload16(p, d); gload16(p + 32768, d + 1024);
  };
  auto stBH = [&](int buf, const char* p) {
    char* d = lds + 65536 + buf * 32768 + 16384 + ldW;
    gload16(p, d); gload16(p + 32768, d + 1024);
  };

  // ---- precomputed DS read offsets (swizzle lane-invariant: row&7 == ln15&7) ----
  int sw = (ln15 & 7) << 4;
  uint32_t aoff0 = (uint32_t)((wr * 64 + ln15) * 128 + ((g16 * 16) ^ sw));
  uint32_t aoff1 = (uint32_t)((wr * 64 + ln15) * 128 + ((64 + g16 * 16) ^ sw));
  uint32_t boff0 = (uint32_t)(65536 + (wc * 64 + ln15) * 128 + ((g16 * 16) ^ sw));
  uint32_t boff1 = (uint32_t)(65536 + (wc * 64 + ln15) * 128 + ((64 + g16 * 16) ^ sw));

  f32x4 zero = {0.f, 0.f, 0.f, 0.f};
  f32x4 acc_a[4][4], acc_g[4][4];
#pragma unroll
  for (int mi = 0; mi < 4; ++mi)
#pragma unroll
    for (int ni = 0; ni < 4; ++ni) { acc_a[mi][ni] = zero; acc_g[mi][ni] = zero; }

  short8 faA[4][2], faB[4][2];     // fa current/next (register dbuf)
  short8 fblA[2][2], fblB[2][2];   // fb n-lo current/next
  short8 fbh[2][2];                // fb n-hi (read P1, used P2..P4)
  short8 fga[2][2], fgb[2][2];     // fg mi0-1 / mi2-3

  auto READ_FA = [&](int buf, short8 (&fa)[4][2]) {
#pragma unroll
    for (int mi = 0; mi < 4; ++mi) {
      fa[mi][0] = *(const short8*)(lds + buf * 32768 + mi * 2048 + aoff0);
      fa[mi][1] = *(const short8*)(lds + buf * 32768 + mi * 2048 + aoff1);
    }
  };
  auto READ_FBL = [&](int buf, short8 (&fbl)[2][2]) {
#pragma unroll
    for (int ni = 0; ni < 2; ++ni) {
      fbl[ni][0] = *(const short8*)(lds + buf * 32768 + ni * 2048 + boff0);
      fbl[ni][1] = *(const short8*)(lds + buf * 32768 + ni * 2048 + boff1);
    }
  };

  // ---- prologue: tile0 full + tile1 minus BH; land tile0; pre-read fa(0), fbl(0) ----
  stAA(0, pAA); stBL(0, pBL); stAG(0, pAG); stBH(0, pBH);
  stAA(1, pAA + 128); stBL(1, pBL + 128); stAG(1, pAG + 128);
  pAA += 256; pBL += 256; pAG += 256; pBH += 128;
  asm volatile("s_waitcnt vmcnt(6)" ::: "memory");
  __builtin_amdgcn_s_barrier();
  READ_FA(0, faA);
  READ_FBL(0, fblA);

  auto KTILE = [&](int t, int cur,
                   short8 (&fa_c)[4][2], short8 (&fa_n)[4][2],
                   short8 (&fbl_c)[2][2], short8 (&fbl_n)[2][2]) {
    // P1: rd fbh; stage BH(t+1)->other; bar; MFMA a x nlo; bar.
#pragma unroll
    for (int j = 0; j < 2; ++j) {
      fbh[j][0] = *(const short8*)(lds + cur * 32768 + (j + 2) * 2048 + boff0);
      fbh[j][1] = *(const short8*)(lds + cur * 32768 + (j + 2) * 2048 + boff1);
    }
    if (t < 31) stBH(cur ^ 1, pBH);
    __builtin_amdgcn_s_barrier();
    __builtin_amdgcn_s_setprio(1);
#pragma unroll
    for (int mi = 0; mi < 4; ++mi)
#pragma unroll
      for (int ni = 0; ni < 2; ++ni)
#pragma unroll
        for (int kk = 0; kk < 2; ++kk)
          acc_a[mi][ni] = __builtin_amdgcn_mfma_f32_16x16x32_bf16(fa_c[mi][kk], fbl_c[ni][kk], acc_a[mi][ni], 0, 0, 0);
    __builtin_amdgcn_s_setprio(0);
    __builtin_amdgcn_s_barrier();

    // P2: rd fga (mi0-1); stage AA(t+2)->cur; bar; MFMA a x nhi; bar.
#pragma unroll
    for (int j = 0; j < 2; ++j) {
      fga[j][0] = *(const short8*)(lds + cur * 32768 + 16384 + j * 2048 + aoff0);
      fga[j][1] = *(const short8*)(lds + cur * 32768 + 16384 + j * 2048 + aoff1);
    }
    if (t < 30) stAA(cur, pAA);
    __builtin_amdgcn_s_barrier();
    __builtin_amdgcn_s_setprio(1);
#pragma unroll
    for (int mi = 0; mi < 4; ++mi)
#pragma unroll
      for (int j = 0; j < 2; ++j)
#pragma unroll
        for (int kk = 0; kk < 2; ++kk)
          acc_a[mi][j + 2] = __builtin_amdgcn_mfma_f32_16x16x32_bf16(fa_c[mi][kk], fbh[j][kk], acc_a[mi][j + 2], 0, 0, 0);
    __builtin_amdgcn_s_setprio(0);
    __builtin_amdgcn_s_barrier();

    // P3: rd fgb (mi2-3); stage BL(t+2)->cur; bar; MFMA g[mi0-1] x all-n; bar.
#pragma unroll
    for (int j = 0; j < 2; ++j) {
      fgb[j][0] = *(const short8*)(lds + cur * 32768 + 16384 + (j + 2) * 2048 + aoff0);
      fgb[j][1] = *(const short8*)(lds + cur * 32768 + 16384 + (j + 2) * 2048 + aoff1);
    }
    if (t < 30) stBL(cur, pBL);
    __builtin_amdgcn_s_barrier();
    __builtin_amdgcn_s_setprio(1);
#pragma unroll
    for (int j = 0; j < 2; ++j)
#pragma unroll
      for (int ni = 0; ni < 2; ++ni)
#pragma unroll
        for (int kk = 0; kk < 2; ++kk) {
          acc_g[j][ni]     = __builtin_amdgcn_mfma_f32_16x16x32_bf16(fga[j][kk], fbl_c[ni][kk], acc_g[j][ni], 0, 0, 0);
          acc_g[j][ni + 2] = __builtin_amdgcn_mfma_f32_16x16x32_bf16(fga[j][kk], fbh[ni][kk], acc_g[j][ni + 2], 0, 0, 0);
        }
    __builtin_amdgcn_s_setprio(0);
    __builtin_amdgcn_s_barrier();

    // P4: stage AG(t+2)->cur; vmcnt; bar; rd fa_n+fbl_n(t+1); MFMA g[mi2-3] x all-n; bar.
    if (t < 30) {
      stAG(cur, pAG);
      asm volatile("s_waitcnt vmcnt(6)" ::: "memory");
    } else {
      asm volatile("s_waitcnt vmcnt(0)" ::: "memory");
    }
    __builtin_amdgcn_s_barrier();
    if (t < 31) { READ_FA(cur ^ 1, fa_n); READ_FBL(cur ^ 1, fbl_n); }
    __builtin_amdgcn_s_setprio(1);
#pragma unroll
    for (int j = 0; j < 2; ++j)
#pragma unroll
      for (int ni = 0; ni < 2; ++ni)
#pragma unroll
        for (int kk = 0; kk < 2; ++kk) {
          acc_g[j + 2][ni]     = __builtin_amdgcn_mfma_f32_16x16x32_bf16(fgb[j][kk], fbl_c[ni][kk], acc_g[j + 2][ni], 0, 0, 0);
          acc_g[j + 2][ni + 2] = __builtin_amdgcn_mfma_f32_16x16x32_bf16(fgb[j][kk], fbh[ni][kk], acc_g[j + 2][ni + 2], 0, 0, 0);
        }
    __builtin_amdgcn_s_setprio(0);
    __builtin_amdgcn_s_barrier();

    pAA += 128; pBL += 128; pAG += 128; pBH += 128;
  };

  for (int tt = 0; tt < 16; ++tt) {
    KTILE(2 * tt, 0, faA, faB, fblA, fblB);
    KTILE(2 * tt + 1, 1, faB, faA, fblB, fblA);
  }

  // ---- epilogue: bias + GLU (a * sigmoid(g)), write f32 out [b][o][l]
#pragma unroll
  for (int mi = 0; mi < 4; ++mi) {
    int ob = mo0 + wr * 64 + mi * 16 + g16 * 4;
    float4 ba4 = *(const float4*)(bout + ob);
    float4 bg4 = *(const float4*)(bout + ob + 2048);
    const float* bap = (const float*)&ba4;
    const float* bgp = (const float*)&bg4;
#pragma unroll
    for (int q = 0; q < 4; ++q) {
      int o = ob + q;
#pragma unroll
      for (int ni = 0; ni < 4; ++ni) {
        float av = acc_a[mi][ni][q] + bap[q];
        float gv = acc_g[mi][ni][q] + bgp[q];
        float res = av / (1.f + expf(-gv));
        int n = n0 + wc * 64 + ni * 16 + ln15;
        out[(size_t)(n >> 12) * 8388608 + (size_t)o * 4096 + (n & 4095)] = res;
      }
    }
  }
}

// ------- K3 v1 (fallback if ws too small for XT): reg-staged GEMM from X [k][n] -------
__global__ __launch_bounds__(256, 2) void gemm_glu_v1(const uint16_t* __restrict__ Wb,
                                                      const uint16_t* __restrict__ X,
                                                      const float* __restrict__ bout,
                                                      float* __restrict__ out) {
  __shared__ char lds[65536];

  int tid = threadIdx.x;
  int lane = tid & 63;
  int wv = tid >> 6;

  int bid = blockIdx.x;
  int wg = (bid & 7) * 256 + (bid >> 3);
  int bm = wg >> 6, bn = wg & 63;
  int m0 = bm * 64, n0 = bn * 128;

  int arb = tid >> 3;
  int ab = (tid & 7) * 16;
  const char* Aglob[4];
  uint32_t AwAddr[4];
#pragma unroll
  for (int i = 0; i < 4; ++i) {
    int r = i * 32 + arb;
    int o = (r < 64) ? (m0 + r) : (2048 + m0 + (r - 64));
    Aglob[i] = (const char*)Wb + (size_t)o * 4096 + ab;
    AwAddr[i] = (uint32_t)(r * 128 + (ab ^ ((r & 7) << 4)));
  }
  int n4 = (tid & 31) * 4;
  int kg = (tid >> 5) * 8;
  const char* Bglob = (const char*)X + ((size_t)kg * 8192 + (size_t)(n0 + n4)) * 2;
  uint32_t BwAddr[4];
#pragma unroll
  for (int no = 0; no < 4; ++no) {
    int n = n4 + no;
    BwAddr[no] = (uint32_t)(n * 128 + (((tid >> 5) * 16) ^ (swzB(n) << 4)));
  }

  f32x4 zero = {0.f, 0.f, 0.f, 0.f};
  f32x4 acc_a[2][4], acc_g[2][4];
#pragma unroll
  for (int mi = 0; mi < 2; ++mi)
#pragma unroll
    for (int ni = 0; ni < 4; ++ni) { acc_a[mi][ni] = zero; acc_g[mi][ni] = zero; }

  uint4 aR[4];
  uint2 bR[8];
  auto LOAD = [&](int t) {
    size_t koff = (size_t)t * 128;
#pragma unroll
    for (int i = 0; i < 4; ++i) aR[i] = *(const uint4*)(Aglob[i] + koff);
    size_t bko = (size_t)t * 64 * 16384;
#pragma unroll
    for (int i = 0; i < 8; ++i) bR[i] = *(const uint2*)(Bglob + bko + (size_t)i * 16384);
  };
  auto WRITE = [&](int buf) {
    char* A = lds + buf * 16384;
#pragma unroll
    for (int i = 0; i < 4; ++i) *(uint4*)(A + AwAddr[i]) = aR[i];
    char* Bb = lds + 32768 + buf * 16384;
    {
      uint4 q; q.x = pack_lo(bR[0].x, bR[1].x); q.y = pack_lo(bR[2].x, bR[3].x);
      q.z = pack_lo(bR[4].x, bR[5].x); q.w = pack_lo(bR[6].x, bR[7].x);
      *(uint4*)(Bb + BwAddr[0]) = q;
    }
    {
      uint4 q; q.x = pack_hi(bR[0].x, bR[1].x); q.y = pack_hi(bR[2].x, bR[3].x);
      q.z = pack_hi(bR[4].x, bR[5].x); q.w = pack_hi(bR[6].x, bR[7].x);
      *(uint4*)(Bb + BwAddr[1]) = q;
    }
    {
      uint4 q; q.x = pack_lo(bR[0].y, bR[1].y); q.y = pack_lo(bR[2].y, bR[3].y);
      q.z = pack_lo(bR[4].y, bR[5].y); q.w = pack_lo(bR[6].y, bR[7].y);
      *(uint4*)(Bb + BwAddr[2]) = q;
    }
    {
      uint4 q; q.x = pack_hi(bR[0].y, bR[1].y); q.y = pack_hi(bR[2].y, bR[3].y);
      q.z = pack_hi(bR[4].y, bR[5].y); q.w = pack_hi(bR[6].y, bR[7].y);
      *(uint4*)(Bb + BwAddr[3]) = q;
    }
  };

  LOAD(0);
  WRITE(0);
  __syncthreads();

  for (int t = 0; t < 32; ++t) {
    int cur = t & 1;
    if (t < 31) LOAD(t + 1);

    const char* A = lds + cur * 16384;
    const char* Bb = lds + 32768 + cur * 16384;
#pragma unroll
    for (int kk = 0; kk < 2; ++kk) {
      int kbyte = kk * 64 + ((lane >> 4) << 4);
      short8 fa[2], fg[2], fb[4];
#pragma unroll
      for (int mi = 0; mi < 2; ++mi) {
        int ra = (wv >> 1) * 32 + mi * 16 + (lane & 15);
        fa[mi] = *(const short8*)(A + ra * 128 + (kbyte ^ ((ra & 7) << 4)));
        int rg = 64 + ra;
        fg[mi] = *(const short8*)(A + rg * 128 + (kbyte ^ ((rg & 7) << 4)));
      }
#pragma unroll
      for (int ni = 0; ni < 4; ++ni) {
        int n = (wv & 1) * 64 + ni * 16 + (lane & 15);
        fb[ni] = *(const short8*)(Bb + n * 128 + (kbyte ^ (swzB(n) << 4)));
      }
#pragma unroll
      for (int mi = 0; mi < 2; ++mi)
#pragma unroll
        for (int ni = 0; ni < 4; ++ni) {
          acc_a[mi][ni] = __builtin_amdgcn_mfma_f32_16x16x32_bf16(fa[mi], fb[ni], acc_a[mi][ni], 0, 0, 0);
          acc_g[mi][ni] = __builtin_amdgcn_mfma_f32_16x16x32_bf16(fg[mi], fb[ni], acc_g[mi][ni], 0, 0, 0);
        }
    }

    if (t < 31) WRITE(cur ^ 1);
    __syncthreads();
  }

  int colb = n0 + (wv & 1) * 64;
#pragma unroll
  for (int mi = 0; mi < 2; ++mi) {
    int ob = m0 + (wv >> 1) * 32 + mi * 16 + ((lane >> 4) << 2);
#pragma unroll
    for (int q = 0; q < 4; ++q) {
      int o = ob + q;
      float ba = bout[o];
      float bg = bout[o + 2048];
#pragma unroll
      for (int ni = 0; ni < 4; ++ni) {
        float av = acc_a[mi][ni][q] + ba;
        float gv = acc_g[mi][ni][q] + bg;
        float res = av / (1.f + expf(-gv));
        int n = colb + ni * 16 + (lane & 15);
        out[(size_t)(n >> 12) * 8388608 + (size_t)o * 4096 + (n & 4095)] = res;
      }
    }
  }
}

extern "C" void kernel_launch(void* const* d_in, const int* in_sizes, int n_in,
                              void* d_out, int out_size, void* d_ws, size_t ws_size,
                              hipStream_t stream) {
  const float* u    = (const float*)d_in[0];
  const float* kern = (const float*)d_in[1];
  const float* D    = (const float*)d_in[2];
  const float* W    = (const float*)d_in[3];
  const float* bo   = (const float*)d_in[4];
  float* out = (float*)d_out;

  uint16_t* Wb = (uint16_t*)d_ws;                                      // 16 MB @ 0
  uint16_t* X  = (uint16_t*)((char*)d_ws + (size_t)16 * 1024 * 1024);  // 32 MB @ 16M
  uint16_t* XT = (uint16_t*)((char*)d_ws + (size_t)48 * 1024 * 1024);  // 32 MB @ 48M

  hipLaunchKernelGGL(conv_cast_kernel, dim3(8192), dim3(256), 0, stream, u, kern, D, X, W, Wb);
  if (ws_size >= (size_t)80 * 1024 * 1024) {
    hipLaunchKernelGGL(transpose_kernel, dim3(4096), dim3(256), 0, stream, X, XT);
    hipLaunchKernelGGL(gemm_glu_v13,     dim3(512),  dim3(512), 0, stream, Wb, XT, bo, out);
  } else {
    hipLaunchKernelGGL(gemm_glu_v1,      dim3(2048), dim3(256), 0, stream, Wb, X, bo, out);
  }
}

// Round 14
// 166.347 us; speedup vs baseline: 1.0234x; 1.0234x over previous
//
#include <hip/hip_runtime.h>
#include <stdint.h>

typedef short short8 __attribute__((ext_vector_type(8)));
typedef float f32x4 __attribute__((ext_vector_type(4)));

#define KLAM 0.003f
// B=2, H=2048, L=4096, Lk=128, N = B*L = 8192, M2 = 2H = 4096

__device__ __forceinline__ uint16_t f2bf(float f) {
  union { float f; uint32_t u; } v; v.f = f;
  uint32_t r = v.u + 0x7fffu + ((v.u >> 16) & 1u);  // RNE
  return (uint16_t)(r >> 16);
}
__device__ __forceinline__ uint32_t pack_lo(uint32_t a, uint32_t b) { return (a & 0xffffu) | (b << 16); }
__device__ __forceinline__ uint32_t pack_hi(uint32_t a, uint32_t b) { return (a >> 16) | (b & 0xffff0000u); }
__device__ __forceinline__ int swzB(int n) { return ((n & 7) ^ ((n >> 3) & 7)); }

typedef __attribute__((address_space(3))) uint32_t* lds_u32p;
typedef const __attribute__((address_space(1))) uint32_t* gbl_u32p;
__device__ __forceinline__ void gload16(const void* g, void* l) {
  __builtin_amdgcn_global_load_lds((gbl_u32p)g, (lds_u32p)l, 16, 0, 0);
}

// ------- K2 (merged): blocks 0..4095 = depthwise FIR + u*D + GeLU; 4096..8191 = cast W -------
__global__ __launch_bounds__(256) void conv_cast_kernel(const float* __restrict__ u,
                                                        const float* __restrict__ kern,
                                                        const float* __restrict__ D,
                                                        uint16_t* __restrict__ X,
                                                        const float* __restrict__ W,
                                                        uint16_t* __restrict__ Wb) {
  int bid = blockIdx.x;
  if (bid >= 4096) {
    int i = ((bid - 4096) * 256 + threadIdx.x) * 8;
    float4 f0 = *(const float4*)(W + i);
    float4 f1 = *(const float4*)(W + i + 4);
    uint4 q;
    q.x = (uint32_t)f2bf(f0.x) | ((uint32_t)f2bf(f0.y) << 16);
    q.y = (uint32_t)f2bf(f0.z) | ((uint32_t)f2bf(f0.w) << 16);
    q.z = (uint32_t)f2bf(f1.x) | ((uint32_t)f2bf(f1.y) << 16);
    q.w = (uint32_t)f2bf(f1.z) | ((uint32_t)f2bf(f1.w) << 16);
    *(uint4*)(Wb + i) = q;
    return;
  }

  __shared__ __align__(16) float su[4096];
  __shared__ __align__(16) uint16_t ubf[4256];
  __shared__ __align__(16) uint16_t kR[176];
  __shared__ __align__(16) uint16_t stg[4][256];

  int tid = threadIdx.x;
  int bh = bid;
  int h = bh & 2047;
  int b = bh >> 11;
  int lane = tid & 63;
  int wv = tid >> 6;
  int ln15 = lane & 15;
  int g = lane >> 4;

  const float4* u4 = (const float4*)(u + (size_t)bh * 4096);
#pragma unroll
  for (int i = 0; i < 4; ++i) {
    float4 v = u4[i * 256 + tid];
    ((float4*)su)[i * 256 + tid] = v;
    uint2 p;
    p.x = (uint32_t)f2bf(v.x) | ((uint32_t)f2bf(v.y) << 16);
    p.y = (uint32_t)f2bf(v.z) | ((uint32_t)f2bf(v.w) << 16);
    *(uint2*)(ubf + 160 + (i * 256 + tid) * 4) = p;
  }
  if (tid < 40) { uint2 z; z.x = 0; z.y = 0; *(uint2*)(ubf + tid * 4) = z; }
  if (tid < 176) {
    int i = 159 - tid;
    uint16_t r = 0;
    if (i >= 0 && i < 128) {
      float kv = kern[h * 128 + i];
      float a = fabsf(kv) - KLAM;
      float s = (a > 0.f) ? (kv > 0.f ? a : -a) : 0.f;
      r = f2bf(s);
    }
    kR[tid] = r;
  }
  __syncthreads();

  float Dh = D[h];

  short8 bfr[5];
#pragma unroll
  for (int q = 0; q < 5; ++q) {
    int z0 = 143 - 32 * q - ln15 + 8 * g;
    union { short8 v; uint16_t s[8]; } t;
#pragma unroll
    for (int e = 0; e < 8; ++e) t.s[e] = kR[z0 + e];
    bfr[q] = t.v;
  }

#pragma unroll
  for (int it = 0; it < 4; ++it) {
    int T0 = (wv * 4 + it) * 256;
    f32x4 acc = {0.f, 0.f, 0.f, 0.f};
#pragma unroll
    for (int q = 0; q < 5; ++q) {
      const short8 a = *(const short8*)(ubf + 160 + T0 + 16 * ln15 - 16 - 32 * q + 8 * g);
      acc = __builtin_amdgcn_mfma_f32_16x16x32_bf16(a, bfr[q], acc, 0, 0, 0);
    }
#pragma unroll
    for (int r = 0; r < 4; ++r) {
      int m = 4 * g + r;
      int t = T0 + 16 * m + ln15;
      float y = acc[r] + Dh * su[t];
      float ge = 0.5f * y * (1.f + erff(y * 0.70710678118654752f));
      stg[wv][16 * m + ln15] = f2bf(ge);
    }
    uint2 v = *(uint2*)(&stg[wv][lane * 4]);
    *(uint2*)(X + (size_t)h * 8192 + (size_t)b * 4096 + T0 + lane * 4) = v;
  }
}

// ------- K2b: transpose X [2048][8192] -> XT [8192][2048] (bf16) -------
__global__ __launch_bounds__(256) void transpose_kernel(const uint16_t* __restrict__ X,
                                                        uint16_t* __restrict__ XT) {
  __shared__ uint16_t t[64][66];
  int tid = threadIdx.x;
  int bn = blockIdx.x & 127;   // n-tile
  int bk = blockIdx.x >> 7;    // k-tile
  int n0 = bn << 6, k0 = bk << 6;
  int cr = tid >> 3;           // 0..31
  int cc = (tid & 7) * 8;      // 0..56
#pragma unroll
  for (int p = 0; p < 2; ++p) {
    int kr = p * 32 + cr;
    uint4 v = *(const uint4*)(X + (size_t)(k0 + kr) * 8192 + n0 + cc);
    const uint16_t* s = (const uint16_t*)&v;
#pragma unroll
    for (int e = 0; e < 8; ++e) t[cc + e][kr] = s[e];
  }
  __syncthreads();
#pragma unroll
  for (int p = 0; p < 2; ++p) {
    int nl = p * 32 + cr;
    uint16_t d[8];
#pragma unroll
    for (int e = 0; e < 8; ++e) d[e] = t[nl][cc + e];
    *(uint4*)(XT + (size_t)(n0 + nl) * 2048 + k0 + cc) = *(uint4*)d;
  }
}

// ------- K3 v12 (best measured): v9 + P4 read-ahead of fa(t+1) -------
// P1: rd fbLO(4); stage BH(t+1); bar; MFMA a x lo (fa pre-read); bar.
// P2: rd fbHI(4); stage AA(t+2); bar; MFMA a x hi; bar.
// P3: rd fg(8);  stage BL(t+2); bar; MFMA g x lo; bar.
// P4: stage AG(t+2); vmcnt(6); bar; rd fa(t+1)<-other buf; MFMA g x hi; bar.
// No manual lgkm anywhere; compiler emits counted waits.
__global__ __launch_bounds__(512, 2) void gemm_glu_v12(const uint16_t* __restrict__ Wb,
                                                       const uint16_t* __restrict__ XT,
                                                       const float* __restrict__ bout,
                                                       float* __restrict__ out) {
  __shared__ __align__(16) char lds[131072];  // A[2][256][64]bf16 @0, B[2][256][64] @65536

  int tid = threadIdx.x;
  int lane = tid & 63;
  int wv = tid >> 6;          // 0..7
  int wr = wv >> 2;           // 0..1  (M half)
  int wc = wv & 3;            // 0..3  (N quarter)
  int ln15 = lane & 15;
  int g16 = lane >> 4;        // 0..3

  // XCD mapping: each XCD owns 4 bn-columns (XT slice 4MB ~ one L2), sweeps bm.
  int bid = blockIdx.x;
  int xcd = bid & 7, idx = bid >> 3;
  int bn = xcd * 4 + (idx & 3);
  int bm = idx >> 2;
  int mo0 = bm * 128, n0 = bn * 256;

  // ---- staging source pointers (pre-swizzled global, linear LDS dest) ----
  int lr8 = lane >> 3;
  int sb = (((lane & 7) ^ lr8) << 4);
  const char* pAA = (const char*)Wb + (size_t)(mo0 + wv * 16 + lr8) * 4096 + sb;
  const char* pAG = (const char*)Wb + (size_t)(2048 + mo0 + wv * 16 + lr8) * 4096 + sb;
  const char* pBL = (const char*)XT + (size_t)(n0 + wv * 16 + lr8) * 4096 + sb;
  const char* pBH = (const char*)XT + (size_t)(n0 + 128 + wv * 16 + lr8) * 4096 + sb;
  uint32_t ldW = wv * 2048;

  auto stAA = [&](int buf, const char* p) {
    char* d = lds + buf * 32768 + ldW;
    gload16(p, d); gload16(p + 32768, d + 1024);
  };
  auto stAG = [&](int buf, const char* p) {
    char* d = lds + buf * 32768 + 16384 + ldW;
    gload16(p, d); gload16(p + 32768, d + 1024);
  };
  auto stBL = [&](int buf, const char* p) {
    char* d = lds + 65536 + buf * 32768 + ldW;
    gload16(p, d); gload16(p + 32768, d + 1024);
  };
  auto stBH = [&](int buf, const char* p) {
    char* d = lds + 65536 + buf * 32768 + 16384 + ldW;
    gload16(p, d); gload16(p + 32768, d + 1024);
  };

  // ---- precomputed DS read offsets (swizzle lane-invariant: row&7 == ln15&7) ----
  int sw = (ln15 & 7) << 4;
  uint32_t aoff0 = (uint32_t)((wr * 64 + ln15) * 128 + ((g16 * 16) ^ sw));
  uint32_t aoff1 = (uint32_t)((wr * 64 + ln15) * 128 + ((64 + g16 * 16) ^ sw));
  uint32_t boff0 = (uint32_t)(65536 + (wc * 64 + ln15) * 128 + ((g16 * 16) ^ sw));
  uint32_t boff1 = (uint32_t)(65536 + (wc * 64 + ln15) * 128 + ((64 + g16 * 16) ^ sw));

  f32x4 zero = {0.f, 0.f, 0.f, 0.f};
  f32x4 acc_a[4][4], acc_g[4][4];
#pragma unroll
  for (int mi = 0; mi < 4; ++mi)
#pragma unroll
    for (int ni = 0; ni < 4; ++ni) { acc_a[mi][ni] = zero; acc_g[mi][ni] = zero; }

  short8 fa[4][2], fg[4][2], fb[4][2];

  auto READ_FA = [&](int buf) {
#pragma unroll
    for (int mi = 0; mi < 4; ++mi) {
      fa[mi][0] = *(const short8*)(lds + buf * 32768 + mi * 2048 + aoff0);
      fa[mi][1] = *(const short8*)(lds + buf * 32768 + mi * 2048 + aoff1);
    }
  };

  // ---- prologue: tile0 full + tile1 minus BH; land tile0; pre-read fa(0) ----
  stAA(0, pAA); stBL(0, pBL); stAG(0, pAG); stBH(0, pBH);
  stAA(1, pAA + 128); stBL(1, pBL + 128); stAG(1, pAG + 128);
  pAA += 256; pBL += 256; pAG += 256; pBH += 128;
  asm volatile("s_waitcnt vmcnt(6)" ::: "memory");
  __builtin_amdgcn_s_barrier();
  READ_FA(0);

  auto KTILE = [&](int t, int cur) {
    // P1: rd fbLO(4); stage BH(t+1)->other; bar; MFMA a x lo (fa pre-read); bar.
#pragma unroll
    for (int ni = 0; ni < 2; ++ni) {
      fb[ni][0] = *(const short8*)(lds + cur * 32768 + ni * 2048 + boff0);
      fb[ni][1] = *(const short8*)(lds + cur * 32768 + ni * 2048 + boff1);
    }
    if (t < 31) stBH(cur ^ 1, pBH);
    __builtin_amdgcn_s_barrier();
    __builtin_amdgcn_s_setprio(1);
#pragma unroll
    for (int mi = 0; mi < 4; ++mi)
#pragma unroll
      for (int ni = 0; ni < 2; ++ni)
#pragma unroll
        for (int kk = 0; kk < 2; ++kk)
          acc_a[mi][ni] = __builtin_amdgcn_mfma_f32_16x16x32_bf16(fa[mi][kk], fb[ni][kk], acc_a[mi][ni], 0, 0, 0);
    __builtin_amdgcn_s_setprio(0);
    __builtin_amdgcn_s_barrier();

    // P2: rd fbHI(4); stage AA(t+2)->cur; bar; MFMA a x hi; bar.
#pragma unroll
    for (int ni = 2; ni < 4; ++ni) {
      fb[ni][0] = *(const short8*)(lds + cur * 32768 + ni * 2048 + boff0);
      fb[ni][1] = *(const short8*)(lds + cur * 32768 + ni * 2048 + boff1);
    }
    if (t < 30) stAA(cur, pAA);
    __builtin_amdgcn_s_barrier();
    __builtin_amdgcn_s_setprio(1);
#pragma unroll
    for (int mi = 0; mi < 4; ++mi)
#pragma unroll
      for (int ni = 2; ni < 4; ++ni)
#pragma unroll
        for (int kk = 0; kk < 2; ++kk)
          acc_a[mi][ni] = __builtin_amdgcn_mfma_f32_16x16x32_bf16(fa[mi][kk], fb[ni][kk], acc_a[mi][ni], 0, 0, 0);
    __builtin_amdgcn_s_setprio(0);
    __builtin_amdgcn_s_barrier();

    // P3: rd fg(8); stage BL(t+2)->cur; bar; MFMA g x lo; bar.
#pragma unroll
    for (int mi = 0; mi < 4; ++mi) {
      fg[mi][0] = *(const short8*)(lds + cur * 32768 + 16384 + mi * 2048 + aoff0);
      fg[mi][1] = *(const short8*)(lds + cur * 32768 + 16384 + mi * 2048 + aoff1);
    }
    if (t < 30) stBL(cur, pBL);
    __builtin_amdgcn_s_barrier();
    __builtin_amdgcn_s_setprio(1);
#pragma unroll
    for (int mi = 0; mi < 4; ++mi)
#pragma unroll
      for (int ni = 0; ni < 2; ++ni)
#pragma unroll
        for (int kk = 0; kk < 2; ++kk)
          acc_g[mi][ni] = __builtin_amdgcn_mfma_f32_16x16x32_bf16(fg[mi][kk], fb[ni][kk], acc_g[mi][ni], 0, 0, 0);
    __builtin_amdgcn_s_setprio(0);
    __builtin_amdgcn_s_barrier();

    // P4: stage AG(t+2)->cur; vmcnt; bar; rd fa(t+1); MFMA g x hi; bar.
    if (t < 30) {
      stAG(cur, pAG);
      asm volatile("s_waitcnt vmcnt(6)" ::: "memory");
    } else {
      asm volatile("s_waitcnt vmcnt(0)" ::: "memory");
    }
    __builtin_amdgcn_s_barrier();
    if (t < 31) READ_FA(cur ^ 1);   // overlap with MFMA below (no dependency)
    __builtin_amdgcn_s_setprio(1);
#pragma unroll
    for (int mi = 0; mi < 4; ++mi)
#pragma unroll
      for (int ni = 2; ni < 4; ++ni)
#pragma unroll
        for (int kk = 0; kk < 2; ++kk)
          acc_g[mi][ni] = __builtin_amdgcn_mfma_f32_16x16x32_bf16(fg[mi][kk], fb[ni][kk], acc_g[mi][ni], 0, 0, 0);
    __builtin_amdgcn_s_setprio(0);
    __builtin_amdgcn_s_barrier();

    pAA += 128; pBL += 128; pAG += 128; pBH += 128;
  };

  for (int tt = 0; tt < 16; ++tt) {
    KTILE(2 * tt, 0);
    KTILE(2 * tt + 1, 1);
  }

  // ---- epilogue: bias + GLU (a * sigmoid(g)), write f32 out [b][o][l]
#pragma unroll
  for (int mi = 0; mi < 4; ++mi) {
    int ob = mo0 + wr * 64 + mi * 16 + g16 * 4;
    float4 ba4 = *(const float4*)(bout + ob);
    float4 bg4 = *(const float4*)(bout + ob + 2048);
    const float* bap = (const float*)&ba4;
    const float* bgp = (const float*)&bg4;
#pragma unroll
    for (int q = 0; q < 4; ++q) {
      int o = ob + q;
#pragma unroll
      for (int ni = 0; ni < 4; ++ni) {
        float av = acc_a[mi][ni][q] + bap[q];
        float gv = acc_g[mi][ni][q] + bgp[q];
        float res = av / (1.f + __expf(-gv));
        int n = n0 + wc * 64 + ni * 16 + ln15;
        out[(size_t)(n >> 12) * 8388608 + (size_t)o * 4096 + (n & 4095)] = res;
      }
    }
  }
}

// ------- K3 v1 (fallback if ws too small for XT): reg-staged GEMM from X [k][n] -------
__global__ __launch_bounds__(256, 2) void gemm_glu_v1(const uint16_t* __restrict__ Wb,
                                                      const uint16_t* __restrict__ X,
                                                      const float* __restrict__ bout,
                                                      float* __restrict__ out) {
  __shared__ char lds[65536];

  int tid = threadIdx.x;
  int lane = tid & 63;
  int wv = tid >> 6;

  int bid = blockIdx.x;
  int wg = (bid & 7) * 256 + (bid >> 3);
  int bm = wg >> 6, bn = wg & 63;
  int m0 = bm * 64, n0 = bn * 128;

  int arb = tid >> 3;
  int ab = (tid & 7) * 16;
  const char* Aglob[4];
  uint32_t AwAddr[4];
#pragma unroll
  for (int i = 0; i < 4; ++i) {
    int r = i * 32 + arb;
    int o = (r < 64) ? (m0 + r) : (2048 + m0 + (r - 64));
    Aglob[i] = (const char*)Wb + (size_t)o * 4096 + ab;
    AwAddr[i] = (uint32_t)(r * 128 + (ab ^ ((r & 7) << 4)));
  }
  int n4 = (tid & 31) * 4;
  int kg = (tid >> 5) * 8;
  const char* Bglob = (const char*)X + ((size_t)kg * 8192 + (size_t)(n0 + n4)) * 2;
  uint32_t BwAddr[4];
#pragma unroll
  for (int no = 0; no < 4; ++no) {
    int n = n4 + no;
    BwAddr[no] = (uint32_t)(n * 128 + (((tid >> 5) * 16) ^ (swzB(n) << 4)));
  }

  f32x4 zero = {0.f, 0.f, 0.f, 0.f};
  f32x4 acc_a[2][4], acc_g[2][4];
#pragma unroll
  for (int mi = 0; mi < 2; ++mi)
#pragma unroll
    for (int ni = 0; ni < 4; ++ni) { acc_a[mi][ni] = zero; acc_g[mi][ni] = zero; }

  uint4 aR[4];
  uint2 bR[8];
  auto LOAD = [&](int t) {
    size_t koff = (size_t)t * 128;
#pragma unroll
    for (int i = 0; i < 4; ++i) aR[i] = *(const uint4*)(Aglob[i] + koff);
    size_t bko = (size_t)t * 64 * 16384;
#pragma unroll
    for (int i = 0; i < 8; ++i) bR[i] = *(const uint2*)(Bglob + bko + (size_t)i * 16384);
  };
  auto WRITE = [&](int buf) {
    char* A = lds + buf * 16384;
#pragma unroll
    for (int i = 0; i < 4; ++i) *(uint4*)(A + AwAddr[i]) = aR[i];
    char* Bb = lds + 32768 + buf * 16384;
    {
      uint4 q; q.x = pack_lo(bR[0].x, bR[1].x); q.y = pack_lo(bR[2].x, bR[3].x);
      q.z = pack_lo(bR[4].x, bR[5].x); q.w = pack_lo(bR[6].x, bR[7].x);
      *(uint4*)(Bb + BwAddr[0]) = q;
    }
    {
      uint4 q; q.x = pack_hi(bR[0].x, bR[1].x); q.y = pack_hi(bR[2].x, bR[3].x);
      q.z = pack_hi(bR[4].x, bR[5].x); q.w = pack_hi(bR[6].x, bR[7].x);
      *(uint4*)(Bb + BwAddr[1]) = q;
    }
    {
      uint4 q; q.x = pack_lo(bR[0].y, bR[1].y); q.y = pack_lo(bR[2].y, bR[3].y);
      q.z = pack_lo(bR[4].y, bR[5].y); q.w = pack_lo(bR[6].y, bR[7].y);
      *(uint4*)(Bb + BwAddr[2]) = q;
    }
    {
      uint4 q; q.x = pack_hi(bR[0].y, bR[1].y); q.y = pack_hi(bR[2].y, bR[3].y);
      q.z = pack_hi(bR[4].y, bR[5].y); q.w = pack_hi(bR[6].y, bR[7].y);
      *(uint4*)(Bb + BwAddr[3]) = q;
    }
  };

  LOAD(0);
  WRITE(0);
  __syncthreads();

  for (int t = 0; t < 32; ++t) {
    int cur = t & 1;
    if (t < 31) LOAD(t + 1);

    const char* A = lds + cur * 16384;
    const char* Bb = lds + 32768 + cur * 16384;
#pragma unroll
    for (int kk = 0; kk < 2; ++kk) {
      int kbyte = kk * 64 + ((lane >> 4) << 4);
      short8 fa[2], fg[2], fb[4];
#pragma unroll
      for (int mi = 0; mi < 2; ++mi) {
        int ra = (wv >> 1) * 32 + mi * 16 + (lane & 15);
        fa[mi] = *(const short8*)(A + ra * 128 + (kbyte ^ ((ra & 7) << 4)));
        int rg = 64 + ra;
        fg[mi] = *(const short8*)(A + rg * 128 + (kbyte ^ ((rg & 7) << 4)));
      }
#pragma unroll
      for (int ni = 0; ni < 4; ++ni) {
        int n = (wv & 1) * 64 + ni * 16 + (lane & 15);
        fb[ni] = *(const short8*)(Bb + n * 128 + (kbyte ^ (swzB(n) << 4)));
      }
#pragma unroll
      for (int mi = 0; mi < 2; ++mi)
#pragma unroll
        for (int ni = 0; ni < 4; ++ni) {
          acc_a[mi][ni] = __builtin_amdgcn_mfma_f32_16x16x32_bf16(fa[mi], fb[ni], acc_a[mi][ni], 0, 0, 0);
          acc_g[mi][ni] = __builtin_amdgcn_mfma_f32_16x16x32_bf16(fg[mi], fb[ni], acc_g[mi][ni], 0, 0, 0);
        }
    }

    if (t < 31) WRITE(cur ^ 1);
    __syncthreads();
  }

  int colb = n0 + (wv & 1) * 64;
#pragma unroll
  for (int mi = 0; mi < 2; ++mi) {
    int ob = m0 + (wv >> 1) * 32 + mi * 16 + ((lane >> 4) << 2);
#pragma unroll
    for (int q = 0; q < 4; ++q) {
      int o = ob + q;
      float ba = bout[o];
      float bg = bout[o + 2048];
#pragma unroll
      for (int ni = 0; ni < 4; ++ni) {
        float av = acc_a[mi][ni][q] + ba;
        float gv = acc_g[mi][ni][q] + bg;
        float res = av / (1.f + __expf(-gv));
        int n = colb + ni * 16 + (lane & 15);
        out[(size_t)(n >> 12) * 8388608 + (size_t)o * 4096 + (n & 4095)] = res;
      }
    }
  }
}

extern "C" void kernel_launch(void* const* d_in, const int* in_sizes, int n_in,
                              void* d_out, int out_size, void* d_ws, size_t ws_size,
                              hipStream_t stream) {
  const float* u    = (const float*)d_in[0];
  const float* kern = (const float*)d_in[1];
  const float* D    = (const float*)d_in[2];
  const float* W    = (const float*)d_in[3];
  const float* bo   = (const float*)d_in[4];
  float* out = (float*)d_out;

  uint16_t* Wb = (uint16_t*)d_ws;                                      // 16 MB @ 0
  uint16_t* X  = (uint16_t*)((char*)d_ws + (size_t)16 * 1024 * 1024);  // 32 MB @ 16M
  uint16_t* XT = (uint16_t*)((char*)d_ws + (size_t)48 * 1024 * 1024);  // 32 MB @ 48M

  hipLaunchKernelGGL(conv_cast_kernel, dim3(8192), dim3(256), 0, stream, u, kern, D, X, W, Wb);
  if (ws_size >= (size_t)80 * 1024 * 1024) {
    hipLaunchKernelGGL(transpose_kernel, dim3(4096), dim3(256), 0, stream, X, XT);
    hipLaunchKernelGGL(gemm_glu_v12,     dim3(512),  dim3(512), 0, stream, Wb, XT, bo, out);
  } else {
    hipLaunchKernelGGL(gemm_glu_v1,      dim3(2048), dim3(256), 0, stream, Wb, X, bo, out);
  }
}